// Round 1
// baseline (816.872 us; speedup 1.0000x reference)
//
#include <hip/hip_runtime.h>
#include <hip/hip_bf16.h>

// Problem constants (fixed by reference)
constexpr int kB = 4096;
constexpr int kD = 512;
constexpr int kH = 512;
constexpr int kS = 16;
constexpr int kG = 2048;   // 4*H

typedef __attribute__((ext_vector_type(8))) short bf16x8_t;
typedef __attribute__((ext_vector_type(4))) float f32x4_t;

__device__ __forceinline__ short f2bf(float x) {
  __hip_bfloat16 h = __float2bfloat16(x);
  return *reinterpret_cast<short*>(&h);
}
__device__ __forceinline__ float sigm(float x) { return 1.0f / (1.0f + expf(-x)); }

// ---------------- event detection + new_ptr (precision-critical: f32) ------
__global__ void event_kernel(const float* __restrict__ x,
                             const float* __restrict__ edW,
                             const float* __restrict__ edb,
                             const int* __restrict__ ptr,
                             int* __restrict__ ev,
                             float* __restrict__ newptr_out)
{
  int b = blockIdx.x * 4 + (threadIdx.x >> 6);
  int lane = threadIdx.x & 63;
  const float* xr = x + (size_t)b * kD;
  float sum = 0.f;
  for (int k = lane; k < kD; k += 64) sum += xr[k] * edW[k];
  #pragma unroll
  for (int off = 32; off; off >>= 1) sum += __shfl_down(sum, off, 64);
  if (lane == 0) {
    float e = sigm(sum + edb[0]);
    int evt = (e > 0.85f) ? 1 : 0;
    ev[b] = evt;
    newptr_out[b] = (float)((ptr[b] + evt) & (kS - 1));
  }
}

// ---------------- f32 -> bf16 convert (vectorized) --------------------------
__global__ void f2b_kernel(const float* __restrict__ src, short* __restrict__ dst, int n4)
{
  int i = blockIdx.x * blockDim.x + threadIdx.x;
  if (i >= n4) return;
  const float4 v = reinterpret_cast<const float4*>(src)[i];
  short4 o;
  o.x = f2bf(v.x); o.y = f2bf(v.y); o.z = f2bf(v.z); o.w = f2bf(v.w);
  reinterpret_cast<short4*>(dst)[i] = o;
}

// ---------------- pack [W1 | W2] rows into bf16 (N x (w1+w2)) ---------------
__global__ void packw_kernel(const float* __restrict__ W1, int w1,
                             const float* __restrict__ W2, int w2,
                             short* __restrict__ dst, int total4)
{
  int i = blockIdx.x * blockDim.x + threadIdx.x;
  if (i >= total4) return;
  long e = (long)i * 4;
  int K = w1 + w2;
  long row = e / K;
  int col = (int)(e - row * K);
  const float* src = (col < w1) ? (W1 + row * (long)w1 + col)
                                : (W2 + row * (long)w2 + (col - w1));
  const float4 v = *reinterpret_cast<const float4*>(src);
  short4 o; o.x=f2bf(v.x); o.y=f2bf(v.y); o.z=f2bf(v.z); o.w=f2bf(v.w);
  *reinterpret_cast<short4*>(dst + e) = o;
}

__global__ void addbias_kernel(const float* __restrict__ a, const float* __restrict__ b,
                               float* __restrict__ o, int n)
{
  int i = blockIdx.x * blockDim.x + threadIdx.x;
  if (i < n) o[i] = a[i] + b[i];
}

// ---------------- slot write + pos_emb add + bf16 staging -------------------
__global__ void slot_update_kernel(const float* __restrict__ slots,
                                   const float* __restrict__ v,
                                   const float* __restrict__ pos_emb,
                                   const int* __restrict__ ptr,
                                   const int* __restrict__ ev,
                                   float* __restrict__ new_slots,
                                   short* __restrict__ slots_pe)
{
  size_t i = (size_t)blockIdx.x * blockDim.x + threadIdx.x;   // one per 4 elems
  size_t e = i * 4;
  int d = (int)(e & (kD - 1));
  size_t bs = e >> 9;
  int s = (int)(bs & (kS - 1));
  size_t b = bs >> 4;
  float4 val;
  if (ev[b] && (ptr[b] == s)) val = *reinterpret_cast<const float4*>(v + (b << 9) + d);
  else                        val = *reinterpret_cast<const float4*>(slots + e);
  *reinterpret_cast<float4*>(new_slots + e) = val;
  const float4 pe = *reinterpret_cast<const float4*>(pos_emb + ((size_t)s << 9) + d);
  short4 o;
  o.x = f2bf(val.x + pe.x); o.y = f2bf(val.y + pe.y);
  o.z = f2bf(val.z + pe.z); o.w = f2bf(val.w + pe.w);
  *reinterpret_cast<short4*>(slots_pe + e) = o;
}

// ---------------- bf16 MFMA GEMM:  C = A @ W^T + bias  ---------------------
// A assembled from up to 3 segments of width 512 each (bf16, per-seg row stride).
// W: bf16, row-major (N x ldw), rows are output columns. C: f32 (M x ldc).
// Tile 128x128, BK=64, 256 threads = 4 waves in 2x2 of 64x64.
__global__ __launch_bounds__(256)
void gemm_bias_kernel(const short* __restrict__ A0, int lda0,
                      const short* __restrict__ A1, int lda1,
                      const short* __restrict__ A2, int lda2,
                      int nseg, const short* __restrict__ W, int ldw,
                      const float* __restrict__ bias,
                      float* __restrict__ C, int ldc)
{
  __shared__ short As[128 * 64];
  __shared__ short Ws[128 * 64];
  const int tid  = threadIdx.x;
  const int wave = tid >> 6;
  const int lane = tid & 63;
  const int wr = wave >> 1;
  const int wc = wave & 1;
  const int row0 = blockIdx.x * 128;
  const int col0 = blockIdx.y * 128;
  const int K = nseg << 9;

  f32x4_t acc[4][4];
  #pragma unroll
  for (int m = 0; m < 4; ++m)
    #pragma unroll
    for (int n = 0; n < 4; ++n)
      acc[m][n] = {0.f, 0.f, 0.f, 0.f};

  const int sr = lane >> 3;        // 0..7 row within 8-row stripe
  const int sc = (lane & 7) * 8;   // col (elements) within 64

  for (int k0 = 0; k0 < K; k0 += 64) {
    const int seg = k0 >> 9;
    const int ks  = k0 & 511;
    const short* Ap = (seg == 0) ? A0 : ((seg == 1) ? A1 : A2);
    const int   lda = (seg == 0) ? lda0 : ((seg == 1) ? lda1 : lda2);
    __syncthreads();
    #pragma unroll
    for (int j = 0; j < 4; ++j) {
      const int arow = wave * 32 + j * 8 + sr;
      const short* asrc = Ap + (size_t)(row0 + arow) * lda + ks + sc;
      __builtin_amdgcn_global_load_lds(
          (const __attribute__((address_space(1))) void*)asrc,
          (__attribute__((address_space(3))) void*)&As[(wave * 32 + j * 8) * 64],
          16, 0, 0);
      const short* wsrc = W + (size_t)(col0 + arow) * ldw + k0 + sc;
      __builtin_amdgcn_global_load_lds(
          (const __attribute__((address_space(1))) void*)wsrc,
          (__attribute__((address_space(3))) void*)&Ws[(wave * 32 + j * 8) * 64],
          16, 0, 0);
    }
    __syncthreads();
    #pragma unroll
    for (int kk = 0; kk < 64; kk += 32) {
      bf16x8_t af[4], bfr[4];
      const int kcol = kk + (lane >> 4) * 8;
      const int ar = wr * 64 + (lane & 15);
      const int br = wc * 64 + (lane & 15);
      #pragma unroll
      for (int m = 0; m < 4; ++m)
        af[m] = *reinterpret_cast<const bf16x8_t*>(&As[(ar + m * 16) * 64 + kcol]);
      #pragma unroll
      for (int n = 0; n < 4; ++n)
        bfr[n] = *reinterpret_cast<const bf16x8_t*>(&Ws[(br + n * 16) * 64 + kcol]);
      #pragma unroll
      for (int m = 0; m < 4; ++m)
        #pragma unroll
        for (int n = 0; n < 4; ++n)
          acc[m][n] = __builtin_amdgcn_mfma_f32_16x16x32_bf16(af[m], bfr[n], acc[m][n], 0, 0, 0);
    }
  }

  #pragma unroll
  for (int n = 0; n < 4; ++n) {
    const int col = col0 + wc * 64 + n * 16 + (lane & 15);
    const float bv = bias[col];
    #pragma unroll
    for (int m = 0; m < 4; ++m) {
      const int rbase = row0 + wr * 64 + m * 16 + (lane >> 4) * 4;
      #pragma unroll
      for (int r = 0; r < 4; ++r)
        C[(size_t)(rbase + r) * ldc + col] = acc[m][n][r] + bv;
    }
  }
}

// ---------------- LSTM elementwise (slot-fuser step) ------------------------
__global__ void step_ew_kernel(const float* __restrict__ gates,
                               float* __restrict__ cbuf,
                               short* __restrict__ hb,
                               float* __restrict__ hmem_out,
                               int first, int last)
{
  size_t idx = (size_t)blockIdx.x * blockDim.x + threadIdx.x;  // B*H
  size_t b = idx >> 9;
  int hc = (int)(idx & (kH - 1));
  const float* g = gates + (b << 11);
  float gi = g[hc], gf = g[hc + 512], gg = g[hc + 1024], go = g[hc + 1536];
  float cp = first ? 0.f : cbuf[idx];
  float cn = sigm(gf) * cp + sigm(gi) * tanhf(gg);
  float hn = sigm(go) * tanhf(cn);
  cbuf[idx] = cn;
  hb[idx] = f2bf(hn);
  if (last) hmem_out[idx] = hn;
}

// ---------------- outer LSTM elementwise ------------------------------------
__global__ void outer_ew_kernel(const float* __restrict__ gates,
                                const float* __restrict__ c_in,
                                float* __restrict__ h_out,
                                float* __restrict__ c_out)
{
  size_t idx = (size_t)blockIdx.x * blockDim.x + threadIdx.x;  // B*H
  size_t b = idx >> 9;
  int hc = (int)(idx & (kH - 1));
  const float* g = gates + (b << 11);
  float cp = c_in[idx];
  float cn = sigm(g[hc + 512]) * cp + sigm(g[hc]) * tanhf(g[hc + 1024]);
  float hn = sigm(g[hc + 1536]) * tanhf(cn);
  c_out[idx] = cn;
  h_out[idx] = hn;
}

// ============================================================================
extern "C" void kernel_launch(void* const* d_in, const int* in_sizes, int n_in,
                              void* d_out, int out_size, void* d_ws, size_t ws_size,
                              hipStream_t stream)
{
  const float* x_t      = (const float*)d_in[0];
  const float* h_lstm   = (const float*)d_in[1];
  const float* c_lstm   = (const float*)d_in[2];
  const float* slots    = (const float*)d_in[3];
  const int*   ptr      = (const int*)  d_in[4];
  const float* value_W  = (const float*)d_in[5];
  const float* value_b  = (const float*)d_in[6];
  const float* ed_W     = (const float*)d_in[7];
  const float* ed_b     = (const float*)d_in[8];
  const float* pos_emb  = (const float*)d_in[9];
  const float* lstm_Wih = (const float*)d_in[10];
  const float* lstm_Whh = (const float*)d_in[11];
  const float* lstm_bih = (const float*)d_in[12];
  const float* lstm_bhh = (const float*)d_in[13];
  const float* Wih      = (const float*)d_in[14];
  const float* bih      = (const float*)d_in[15];
  const float* Whh      = (const float*)d_in[16];

  float* out       = (float*)d_out;
  float* h_new     = out;
  float* c_new     = out + (size_t)kB * kH;
  float* h_mem     = out + (size_t)2 * kB * kH;
  float* new_slots = out + (size_t)3 * kB * kH;
  float* new_ptr   = out + (size_t)3 * kB * kH + (size_t)kB * kS * kD;

  // workspace layout (bytes)
  char* ws = (char*)d_ws;
  size_t off = 0;
  auto alloc = [&](size_t bytes) { void* p = ws + off; off += (bytes + 255) & ~(size_t)255; return p; };
  int*   ev        = (int*)  alloc((size_t)kB * 4);
  short* x_b       = (short*)alloc((size_t)kB * kD * 2);
  short* hlstm_b   = (short*)alloc((size_t)kB * kH * 2);
  short* vW_b      = (short*)alloc((size_t)kD * kD * 2);
  short* stepW_b   = (short*)alloc((size_t)kG * (kD + kH) * 2);
  float* stepBias  = (float*)alloc((size_t)kG * 4);
  short* outerW_b  = (short*)alloc((size_t)kG * (kD + kH + kH) * 2);
  float* v_f32     = (float*)alloc((size_t)kB * kD * 4);
  short* h_b       = (short*)alloc((size_t)kB * kH * 2);
  float* c_f32     = (float*)alloc((size_t)kB * kH * 4);
  float* gates     = (float*)alloc((size_t)kB * kG * 4);
  short* slots_pe  = (short*)alloc((size_t)kB * kS * kD * 2);
  (void)ws_size; (void)in_sizes; (void)n_in; (void)out_size;

  // 1. event flags + new_ptr (f32 exact)
  event_kernel<<<kB / 4, 256, 0, stream>>>(x_t, ed_W, ed_b, ptr, ev, new_ptr);

  // 2. conversions / packing
  f2b_kernel<<<(kB * kD / 4 + 255) / 256, 256, 0, stream>>>(x_t, x_b, kB * kD / 4);
  f2b_kernel<<<(kB * kH / 4 + 255) / 256, 256, 0, stream>>>(h_lstm, hlstm_b, kB * kH / 4);
  f2b_kernel<<<(kD * kD / 4 + 255) / 256, 256, 0, stream>>>(value_W, vW_b, kD * kD / 4);
  packw_kernel<<<(kG * 1024 / 4 + 255) / 256, 256, 0, stream>>>(lstm_Wih, kD, lstm_Whh, kH,
                                                                stepW_b, kG * 1024 / 4);
  packw_kernel<<<(kG * 1536 / 4 + 255) / 256, 256, 0, stream>>>(Wih, kD + kH, Whh, kH,
                                                                outerW_b, kG * 1536 / 4);
  addbias_kernel<<<(kG + 255) / 256, 256, 0, stream>>>(lstm_bih, lstm_bhh, stepBias, kG);

  // 3. v = x @ value_W^T + value_b
  gemm_bias_kernel<<<dim3(kB / 128, kD / 128), 256, 0, stream>>>(
      x_b, kD, nullptr, 0, nullptr, 0, 1, vW_b, kD, value_b, v_f32, kD);

  // 4. new_slots (f32 out) + slots_pe bf16 staging
  slot_update_kernel<<<(int)((size_t)kB * kS * kD / 4 / 256), 256, 0, stream>>>(
      slots, v_f32, pos_emb, ptr, ev, new_slots, slots_pe);

  // 5. slot-fuser LSTM: 16 sequential steps
  for (int s = 0; s < kS; ++s) {
    const short* a0 = slots_pe + (size_t)s * kD;
    if (s == 0) {
      gemm_bias_kernel<<<dim3(kB / 128, kG / 128), 256, 0, stream>>>(
          a0, kS * kD, nullptr, 0, nullptr, 0, 1, stepW_b, kD + kH, stepBias, gates, kG);
    } else {
      gemm_bias_kernel<<<dim3(kB / 128, kG / 128), 256, 0, stream>>>(
          a0, kS * kD, h_b, kH, nullptr, 0, 2, stepW_b, kD + kH, stepBias, gates, kG);
    }
    step_ew_kernel<<<kB * kH / 256, 256, 0, stream>>>(gates, c_f32, h_b, h_mem,
                                                      s == 0 ? 1 : 0, s == kS - 1 ? 1 : 0);
  }

  // 6. outer LSTM: gates = [x | h_mem | h_lstm] @ [Wih|Whh]^T + bih
  gemm_bias_kernel<<<dim3(kB / 128, kG / 128), 256, 0, stream>>>(
      x_b, kD, h_b, kH, hlstm_b, kH, 3, outerW_b, kD + kH + kH, bih, gates, kG);
  outer_ew_kernel<<<kB * kH / 256, 256, 0, stream>>>(gates, c_lstm, h_new, c_new);
}

// Round 2
// 748.735 us; speedup vs baseline: 1.0910x; 1.0910x over previous
//
#include <hip/hip_runtime.h>
#include <hip/hip_bf16.h>

// Problem constants (fixed by reference)
constexpr int kB = 4096;
constexpr int kD = 512;
constexpr int kH = 512;
constexpr int kS = 16;
constexpr int kG = 2048;   // 4*H

typedef __attribute__((ext_vector_type(8))) short bf16x8_t;
typedef __attribute__((ext_vector_type(4))) float f32x4_t;

__device__ __forceinline__ short f2bf(float x) {
  __hip_bfloat16 h = __float2bfloat16(x);
  return *reinterpret_cast<short*>(&h);
}
__device__ __forceinline__ float sigm(float x) { return 1.0f / (1.0f + expf(-x)); }

// ---------------- event detection + new_ptr (precision-critical: f32) ------
__global__ void event_kernel(const float* __restrict__ x,
                             const float* __restrict__ edW,
                             const float* __restrict__ edb,
                             const int* __restrict__ ptr,
                             int* __restrict__ ev,
                             float* __restrict__ newptr_out)
{
  int b = blockIdx.x * 4 + (threadIdx.x >> 6);
  int lane = threadIdx.x & 63;
  const float* xr = x + (size_t)b * kD;
  float sum = 0.f;
  for (int k = lane; k < kD; k += 64) sum += xr[k] * edW[k];
  #pragma unroll
  for (int off = 32; off; off >>= 1) sum += __shfl_down(sum, off, 64);
  if (lane == 0) {
    float e = sigm(sum + edb[0]);
    int evt = (e > 0.85f) ? 1 : 0;
    ev[b] = evt;
    newptr_out[b] = (float)((ptr[b] + evt) & (kS - 1));
  }
}

// ---------------- f32 -> bf16 convert (vectorized) --------------------------
__global__ void f2b_kernel(const float* __restrict__ src, short* __restrict__ dst, int n4)
{
  int i = blockIdx.x * blockDim.x + threadIdx.x;
  if (i >= n4) return;
  const float4 v = reinterpret_cast<const float4*>(src)[i];
  short4 o;
  o.x = f2bf(v.x); o.y = f2bf(v.y); o.z = f2bf(v.z); o.w = f2bf(v.w);
  reinterpret_cast<short4*>(dst)[i] = o;
}

// ---------------- pack [W1 | W2] rows into bf16 with gate interleave --------
// Packed output col p:  h = (p>>6)*16 + (p&15),  gate = (p>>4)&3.
// Source row r = gate*512 + h (PyTorch i,f,g,o order).
__global__ void packw_gates_kernel(const float* __restrict__ W1, int w1,
                                   const float* __restrict__ W2, int w2,
                                   short* __restrict__ dst, int total4)
{
  int i = blockIdx.x * blockDim.x + threadIdx.x;
  if (i >= total4) return;
  long e = (long)i * 4;
  int K = w1 + w2;
  long p = e / K;                       // packed row (= output col)
  int col = (int)(e - p * K);
  long r = (long)(((p >> 4) & 3) * 512 + ((p >> 6) << 4) + (p & 15));
  const float* src = (col < w1) ? (W1 + r * (long)w1 + col)
                                : (W2 + r * (long)w2 + (col - w1));
  const float4 v = *reinterpret_cast<const float4*>(src);
  short4 o; o.x=f2bf(v.x); o.y=f2bf(v.y); o.z=f2bf(v.z); o.w=f2bf(v.w);
  *reinterpret_cast<short4*>(dst + e) = o;
}

// packed bias: out[p] = b1[r] (+ b2[r])
__global__ void packbias_kernel(const float* __restrict__ b1, const float* __restrict__ b2,
                                float* __restrict__ o, int n)
{
  int p = blockIdx.x * blockDim.x + threadIdx.x;
  if (p >= n) return;
  int r = ((p >> 4) & 3) * 512 + ((p >> 6) << 4) + (p & 15);
  float v = b1[r];
  if (b2) v += b2[r];
  o[p] = v;
}

// ---------------- slot write + pos_emb add + bf16 staging -------------------
__global__ void slot_update_kernel(const float* __restrict__ slots,
                                   const float* __restrict__ v,
                                   const float* __restrict__ pos_emb,
                                   const int* __restrict__ ptr,
                                   const int* __restrict__ ev,
                                   float* __restrict__ new_slots,
                                   short* __restrict__ slots_pe)
{
  size_t i = (size_t)blockIdx.x * blockDim.x + threadIdx.x;   // one per 4 elems
  size_t e = i * 4;
  int d = (int)(e & (kD - 1));
  size_t bs = e >> 9;
  int s = (int)(bs & (kS - 1));
  size_t b = bs >> 4;
  float4 val;
  if (ev[b] && (ptr[b] == s)) val = *reinterpret_cast<const float4*>(v + (b << 9) + d);
  else                        val = *reinterpret_cast<const float4*>(slots + e);
  *reinterpret_cast<float4*>(new_slots + e) = val;
  const float4 pe = *reinterpret_cast<const float4*>(pos_emb + ((size_t)s << 9) + d);
  short4 o;
  o.x = f2bf(val.x + pe.x); o.y = f2bf(val.y + pe.y);
  o.z = f2bf(val.z + pe.z); o.w = f2bf(val.w + pe.w);
  *reinterpret_cast<short4*>(slots_pe + e) = o;
}

// ---------------- bf16 MFMA GEMM with fused epilogue -----------------------
// A assembled from up to 3 segments of width 512 each (bf16, per-seg row stride).
// W: bf16, row-major (N x ldw). Tile 128x128, BK=64, 4 waves (2x2 of 64x64).
// mode 0: C = A@W^T + bias   (plain store to C, ldc)
// mode 1: LSTM step ew. W packed gate-interleaved; fragment n == gate n.
//         cp = first?0:cbuf ; cn,hn ; cbuf=cn, hb=bf16(hn), last->hmem=hn
// mode 2: outer LSTM ew. cp = c_in ; writes c_out, h_out (f32)
__global__ __launch_bounds__(256)
void gemm_fused_kernel(const short* __restrict__ A0, int lda0,
                       const short* __restrict__ A1, int lda1,
                       const short* __restrict__ A2, int lda2,
                       int nseg, const short* __restrict__ W, int ldw,
                       const float* __restrict__ bias, int mode,
                       float* __restrict__ C, int ldc,
                       float* __restrict__ cbuf, short* __restrict__ hb,
                       float* __restrict__ hmem, int first, int last,
                       const float* __restrict__ c_in,
                       float* __restrict__ h_out, float* __restrict__ c_out)
{
  __shared__ short As[128 * 64];
  __shared__ short Ws[128 * 64];
  const int tid  = threadIdx.x;
  const int wave = tid >> 6;
  const int lane = tid & 63;
  const int wr = wave >> 1;
  const int wc = wave & 1;
  const int row0 = blockIdx.x * 128;
  const int col0 = blockIdx.y * 128;
  const int K = nseg << 9;

  f32x4_t acc[4][4];
  #pragma unroll
  for (int m = 0; m < 4; ++m)
    #pragma unroll
    for (int n = 0; n < 4; ++n)
      acc[m][n] = {0.f, 0.f, 0.f, 0.f};

  const int sr = lane >> 3;        // 0..7 row within 8-row stripe
  const int sc = (lane & 7) * 8;   // col (elements) within 64

  for (int k0 = 0; k0 < K; k0 += 64) {
    const int seg = k0 >> 9;
    const int ks  = k0 & 511;
    const short* Ap = (seg == 0) ? A0 : ((seg == 1) ? A1 : A2);
    const int   lda = (seg == 0) ? lda0 : ((seg == 1) ? lda1 : lda2);
    __syncthreads();
    #pragma unroll
    for (int j = 0; j < 4; ++j) {
      const int arow = wave * 32 + j * 8 + sr;
      const short* asrc = Ap + (size_t)(row0 + arow) * lda + ks + sc;
      __builtin_amdgcn_global_load_lds(
          (const __attribute__((address_space(1))) void*)asrc,
          (__attribute__((address_space(3))) void*)&As[(wave * 32 + j * 8) * 64],
          16, 0, 0);
      const short* wsrc = W + (size_t)(col0 + arow) * ldw + k0 + sc;
      __builtin_amdgcn_global_load_lds(
          (const __attribute__((address_space(1))) void*)wsrc,
          (__attribute__((address_space(3))) void*)&Ws[(wave * 32 + j * 8) * 64],
          16, 0, 0);
    }
    __syncthreads();
    #pragma unroll
    for (int kk = 0; kk < 64; kk += 32) {
      bf16x8_t af[4], bfr[4];
      const int kcol = kk + (lane >> 4) * 8;
      const int ar = wr * 64 + (lane & 15);
      const int br = wc * 64 + (lane & 15);
      #pragma unroll
      for (int m = 0; m < 4; ++m)
        af[m] = *reinterpret_cast<const bf16x8_t*>(&As[(ar + m * 16) * 64 + kcol]);
      #pragma unroll
      for (int n = 0; n < 4; ++n)
        bfr[n] = *reinterpret_cast<const bf16x8_t*>(&Ws[(br + n * 16) * 64 + kcol]);
      #pragma unroll
      for (int m = 0; m < 4; ++m)
        #pragma unroll
        for (int n = 0; n < 4; ++n)
          acc[m][n] = __builtin_amdgcn_mfma_f32_16x16x32_bf16(af[m], bfr[n], acc[m][n], 0, 0, 0);
    }
  }

  // ---- epilogue ----
  float bv[4];
  #pragma unroll
  for (int n = 0; n < 4; ++n)
    bv[n] = bias[col0 + wc * 64 + n * 16 + (lane & 15)];

  if (mode == 0) {
    #pragma unroll
    for (int n = 0; n < 4; ++n) {
      const int col = col0 + wc * 64 + n * 16 + (lane & 15);
      #pragma unroll
      for (int m = 0; m < 4; ++m) {
        const int rbase = row0 + wr * 64 + m * 16 + (lane >> 4) * 4;
        #pragma unroll
        for (int r = 0; r < 4; ++r)
          C[(size_t)(rbase + r) * ldc + col] = acc[m][n][r] + bv[n];
      }
    }
    return;
  }

  // LSTM epilogue: fragment n == gate (i,f,g,o); h channel in-lane.
  const int hcol = ((col0 >> 6) + wc) * 16 + (lane & 15);
  #pragma unroll
  for (int m = 0; m < 4; ++m) {
    const int rbase = row0 + wr * 64 + m * 16 + (lane >> 4) * 4;
    #pragma unroll
    for (int r = 0; r < 4; ++r) {
      const size_t idx = (size_t)(rbase + r) * kH + hcol;
      const float gi = acc[m][0][r] + bv[0];
      const float gf = acc[m][1][r] + bv[1];
      const float gg = acc[m][2][r] + bv[2];
      const float go = acc[m][3][r] + bv[3];
      float cp;
      if (mode == 1) cp = first ? 0.f : cbuf[idx];
      else           cp = c_in[idx];
      const float cn = sigm(gf) * cp + sigm(gi) * tanhf(gg);
      const float hn = sigm(go) * tanhf(cn);
      if (mode == 1) {
        cbuf[idx] = cn;
        hb[idx] = f2bf(hn);
        if (last) hmem[idx] = hn;
      } else {
        c_out[idx] = cn;
        h_out[idx] = hn;
      }
    }
  }
}

// ============================================================================
extern "C" void kernel_launch(void* const* d_in, const int* in_sizes, int n_in,
                              void* d_out, int out_size, void* d_ws, size_t ws_size,
                              hipStream_t stream)
{
  const float* x_t      = (const float*)d_in[0];
  const float* h_lstm   = (const float*)d_in[1];
  const float* c_lstm   = (const float*)d_in[2];
  const float* slots    = (const float*)d_in[3];
  const int*   ptr      = (const int*)  d_in[4];
  const float* value_W  = (const float*)d_in[5];
  const float* value_b  = (const float*)d_in[6];
  const float* ed_W     = (const float*)d_in[7];
  const float* ed_b     = (const float*)d_in[8];
  const float* pos_emb  = (const float*)d_in[9];
  const float* lstm_Wih = (const float*)d_in[10];
  const float* lstm_Whh = (const float*)d_in[11];
  const float* lstm_bih = (const float*)d_in[12];
  const float* lstm_bhh = (const float*)d_in[13];
  const float* Wih      = (const float*)d_in[14];
  const float* bih      = (const float*)d_in[15];
  const float* Whh      = (const float*)d_in[16];

  float* out       = (float*)d_out;
  float* h_new     = out;
  float* c_new     = out + (size_t)kB * kH;
  float* h_mem     = out + (size_t)2 * kB * kH;
  float* new_slots = out + (size_t)3 * kB * kH;
  float* new_ptr   = out + (size_t)3 * kB * kH + (size_t)kB * kS * kD;

  // workspace layout (bytes)
  char* ws = (char*)d_ws;
  size_t off = 0;
  auto alloc = [&](size_t bytes) { void* p = ws + off; off += (bytes + 255) & ~(size_t)255; return p; };
  int*   ev        = (int*)  alloc((size_t)kB * 4);
  short* x_b       = (short*)alloc((size_t)kB * kD * 2);
  short* hlstm_b   = (short*)alloc((size_t)kB * kH * 2);
  short* vW_b      = (short*)alloc((size_t)kD * kD * 2);
  short* stepW_b   = (short*)alloc((size_t)kG * (kD + kH) * 2);
  float* stepBias  = (float*)alloc((size_t)kG * 4);
  short* outerW_b  = (short*)alloc((size_t)kG * (kD + kH + kH) * 2);
  float* outerBias = (float*)alloc((size_t)kG * 4);
  float* v_f32     = (float*)alloc((size_t)kB * kD * 4);
  short* h_b       = (short*)alloc((size_t)kB * kH * 2);
  float* c_f32     = (float*)alloc((size_t)kB * kH * 4);
  short* slots_pe  = (short*)alloc((size_t)kB * kS * kD * 2);
  (void)ws_size; (void)in_sizes; (void)n_in; (void)out_size;

  // 1. event flags + new_ptr (f32 exact)
  event_kernel<<<kB / 4, 256, 0, stream>>>(x_t, ed_W, ed_b, ptr, ev, new_ptr);

  // 2. conversions / packing
  f2b_kernel<<<(kB * kD / 4 + 255) / 256, 256, 0, stream>>>(x_t, x_b, kB * kD / 4);
  f2b_kernel<<<(kB * kH / 4 + 255) / 256, 256, 0, stream>>>(h_lstm, hlstm_b, kB * kH / 4);
  f2b_kernel<<<(kD * kD / 4 + 255) / 256, 256, 0, stream>>>(value_W, vW_b, kD * kD / 4);
  packw_gates_kernel<<<(kG * 1024 / 4 + 255) / 256, 256, 0, stream>>>(
      lstm_Wih, kD, lstm_Whh, kH, stepW_b, kG * 1024 / 4);
  packw_gates_kernel<<<(kG * 1536 / 4 + 255) / 256, 256, 0, stream>>>(
      Wih, kD + kH, Whh, kH, outerW_b, kG * 1536 / 4);
  packbias_kernel<<<(kG + 255) / 256, 256, 0, stream>>>(lstm_bih, lstm_bhh, stepBias, kG);
  packbias_kernel<<<(kG + 255) / 256, 256, 0, stream>>>(bih, nullptr, outerBias, kG);

  // 3. v = x @ value_W^T + value_b  (mode 0)
  gemm_fused_kernel<<<dim3(kB / 128, kD / 128), 256, 0, stream>>>(
      x_b, kD, nullptr, 0, nullptr, 0, 1, vW_b, kD, value_b, 0,
      v_f32, kD, nullptr, nullptr, nullptr, 0, 0, nullptr, nullptr, nullptr);

  // 4. new_slots (f32 out) + slots_pe bf16 staging
  slot_update_kernel<<<(int)((size_t)kB * kS * kD / 4 / 256), 256, 0, stream>>>(
      slots, v_f32, pos_emb, ptr, ev, new_slots, slots_pe);

  // 5. slot-fuser LSTM: 16 sequential steps, ew fused into GEMM epilogue
  for (int s = 0; s < kS; ++s) {
    const short* a0 = slots_pe + (size_t)s * kD;
    const int first = (s == 0) ? 1 : 0;
    const int last  = (s == kS - 1) ? 1 : 0;
    if (s == 0) {
      gemm_fused_kernel<<<dim3(kB / 128, kG / 128), 256, 0, stream>>>(
          a0, kS * kD, nullptr, 0, nullptr, 0, 1, stepW_b, kD + kH, stepBias, 1,
          nullptr, 0, c_f32, h_b, h_mem, first, last, nullptr, nullptr, nullptr);
    } else {
      gemm_fused_kernel<<<dim3(kB / 128, kG / 128), 256, 0, stream>>>(
          a0, kS * kD, h_b, kH, nullptr, 0, 2, stepW_b, kD + kH, stepBias, 1,
          nullptr, 0, c_f32, h_b, h_mem, first, last, nullptr, nullptr, nullptr);
    }
  }

  // 6. outer LSTM fused: gates = [x | h_mem | h_lstm] @ [Wih|Whh]^T + bih
  gemm_fused_kernel<<<dim3(kB / 128, kG / 128), 256, 0, stream>>>(
      x_b, kD, h_b, kH, hlstm_b, kH, 3, outerW_b, kD + kH + kH, outerBias, 2,
      nullptr, 0, nullptr, nullptr, nullptr, 0, 0, c_lstm, h_new, c_new);
}

// Round 3
// 688.801 us; speedup vs baseline: 1.1859x; 1.0870x over previous
//
#include <hip/hip_runtime.h>
#include <hip/hip_bf16.h>

// Problem constants (fixed by reference)
constexpr int kB = 4096;
constexpr int kD = 512;
constexpr int kH = 512;
constexpr int kS = 16;
constexpr int kG = 2048;   // 4*H

typedef __attribute__((ext_vector_type(8))) short bf16x8_t;
typedef __attribute__((ext_vector_type(4))) float f32x4_t;

__device__ __forceinline__ short f2bf(float x) {
  __hip_bfloat16 h = __float2bfloat16(x);
  return *reinterpret_cast<short*>(&h);
}
__device__ __forceinline__ float sigm(float x) { return 1.0f / (1.0f + expf(-x)); }

// ---------------- event detection + new_ptr (precision-critical: f32) ------
__global__ void event_kernel(const float* __restrict__ x,
                             const float* __restrict__ edW,
                             const float* __restrict__ edb,
                             const int* __restrict__ ptr,
                             int* __restrict__ ev,
                             float* __restrict__ newptr_out)
{
  int b = blockIdx.x * 4 + (threadIdx.x >> 6);
  int lane = threadIdx.x & 63;
  const float* xr = x + (size_t)b * kD;
  float sum = 0.f;
  for (int k = lane; k < kD; k += 64) sum += xr[k] * edW[k];
  #pragma unroll
  for (int off = 32; off; off >>= 1) sum += __shfl_down(sum, off, 64);
  if (lane == 0) {
    float e = sigm(sum + edb[0]);
    int evt = (e > 0.85f) ? 1 : 0;
    ev[b] = evt;
    newptr_out[b] = (float)((ptr[b] + evt) & (kS - 1));
  }
}

// ---------------- f32 -> bf16 convert (vectorized) --------------------------
__global__ void f2b_kernel(const float* __restrict__ src, short* __restrict__ dst, int n4)
{
  int i = blockIdx.x * blockDim.x + threadIdx.x;
  if (i >= n4) return;
  const float4 v = reinterpret_cast<const float4*>(src)[i];
  short4 o;
  o.x = f2bf(v.x); o.y = f2bf(v.y); o.z = f2bf(v.z); o.w = f2bf(v.w);
  reinterpret_cast<short4*>(dst)[i] = o;
}

// ---------------- pack [W1 | W2] rows into bf16 with gate interleave --------
// Packed output col p:  h = (p>>6)*16 + (p&15),  gate = (p>>4)&3.
// Source row r = gate*512 + h (PyTorch i,f,g,o order).
__global__ void packw_gates_kernel(const float* __restrict__ W1, int w1,
                                   const float* __restrict__ W2, int w2,
                                   short* __restrict__ dst, int total4)
{
  int i = blockIdx.x * blockDim.x + threadIdx.x;
  if (i >= total4) return;
  long e = (long)i * 4;
  int K = w1 + w2;
  long p = e / K;                       // packed row (= output col)
  int col = (int)(e - p * K);
  long r = (long)(((p >> 4) & 3) * 512 + ((p >> 6) << 4) + (p & 15));
  const float* src = (col < w1) ? (W1 + r * (long)w1 + col)
                                : (W2 + r * (long)w2 + (col - w1));
  const float4 v = *reinterpret_cast<const float4*>(src);
  short4 o; o.x=f2bf(v.x); o.y=f2bf(v.y); o.z=f2bf(v.z); o.w=f2bf(v.w);
  *reinterpret_cast<short4*>(dst + e) = o;
}

// packed bias: out[p] = b1[r] (+ b2[r])
__global__ void packbias_kernel(const float* __restrict__ b1, const float* __restrict__ b2,
                                float* __restrict__ o, int n)
{
  int p = blockIdx.x * blockDim.x + threadIdx.x;
  if (p >= n) return;
  int r = ((p >> 4) & 3) * 512 + ((p >> 6) << 4) + (p & 15);
  float v = b1[r];
  if (b2) v += b2[r];
  o[p] = v;
}

// ---------------- slot write + pos_emb add + bf16 staging -------------------
__global__ void slot_update_kernel(const float* __restrict__ slots,
                                   const float* __restrict__ v,
                                   const float* __restrict__ pos_emb,
                                   const int* __restrict__ ptr,
                                   const int* __restrict__ ev,
                                   float* __restrict__ new_slots,
                                   short* __restrict__ slots_pe)
{
  size_t i = (size_t)blockIdx.x * blockDim.x + threadIdx.x;   // one per 4 elems
  size_t e = i * 4;
  int d = (int)(e & (kD - 1));
  size_t bs = e >> 9;
  int s = (int)(bs & (kS - 1));
  size_t b = bs >> 4;
  float4 val;
  if (ev[b] && (ptr[b] == s)) val = *reinterpret_cast<const float4*>(v + (b << 9) + d);
  else                        val = *reinterpret_cast<const float4*>(slots + e);
  *reinterpret_cast<float4*>(new_slots + e) = val;
  const float4 pe = *reinterpret_cast<const float4*>(pos_emb + ((size_t)s << 9) + d);
  short4 o;
  o.x = f2bf(val.x + pe.x); o.y = f2bf(val.y + pe.y);
  o.z = f2bf(val.z + pe.z); o.w = f2bf(val.w + pe.w);
  *reinterpret_cast<short4*>(slots_pe + e) = o;
}

// ---------------- bf16 MFMA GEMM with fused epilogue -----------------------
// Tile 128x64, BK=64. 4 waves, all in M: wave w owns rows [w*32, w*32+32).
// Per-wave output 32x64: m-frags 2, n-frags 4 (n-frag == gate in LSTM modes).
// Grid: 1-D, XCD-chunk swizzled; nby = N/64 col-tiles (bx-major within XCD).
// mode 0: C = A@W^T + bias
// mode 1: LSTM step ew (W gate-packed): cbuf/hb update, last->hmem
// mode 2: outer LSTM ew: c_in -> h_out, c_out
__global__ __launch_bounds__(256, 4)
void gemm_fused_kernel(const short* __restrict__ A0, int lda0,
                       const short* __restrict__ A1, int lda1,
                       const short* __restrict__ A2, int lda2,
                       int nseg, const short* __restrict__ W, int ldw,
                       const float* __restrict__ bias, int mode, int nby,
                       float* __restrict__ C, int ldc,
                       float* __restrict__ cbuf, short* __restrict__ hb,
                       float* __restrict__ hmem, int first, int last,
                       const float* __restrict__ c_in,
                       float* __restrict__ h_out, float* __restrict__ c_out)
{
  __shared__ short As[128 * 64];
  __shared__ short Ws[64 * 64];
  const int tid  = threadIdx.x;
  const int wave = tid >> 6;
  const int lane = tid & 63;

  // XCD-chunked swizzle: 8 XCDs, bx-major within each chunk
  const int nb  = gridDim.x;
  const int vid = (blockIdx.x & 7) * (nb >> 3) + (blockIdx.x >> 3);
  const int bx  = vid / nby;
  const int by  = vid - bx * nby;
  const int row0 = bx * 128;
  const int col0 = by * 64;
  const int K = nseg << 9;

  f32x4_t acc[2][4];
  #pragma unroll
  for (int m = 0; m < 2; ++m)
    #pragma unroll
    for (int n = 0; n < 4; ++n)
      acc[m][n] = {0.f, 0.f, 0.f, 0.f};

  const int srow = tid >> 3;        // 0..31: row within 32-row stage pass
  const int scol = (tid & 7) * 8;   // col (elements) within 64

  for (int k0 = 0; k0 < K; k0 += 64) {
    const int seg = k0 >> 9;
    const int ks  = k0 & 511;
    const short* Ap = (seg == 0) ? A0 : ((seg == 1) ? A1 : A2);
    const int   lda = (seg == 0) ? lda0 : ((seg == 1) ? lda1 : lda2);
    __syncthreads();
    // stage A: 128 rows (4 passes of 32 rows)
    #pragma unroll
    for (int j = 0; j < 4; ++j) {
      const int arow = j * 32 + srow;
      const short* asrc = Ap + (size_t)(row0 + arow) * lda + ks + scol;
      __builtin_amdgcn_global_load_lds(
          (const __attribute__((address_space(1))) void*)asrc,
          (__attribute__((address_space(3))) void*)&As[arow * 64 + scol],
          16, 0, 0);
    }
    // stage W: 64 rows (2 passes of 32 rows)
    #pragma unroll
    for (int j = 0; j < 2; ++j) {
      const int wrow = j * 32 + srow;
      const short* wsrc = W + (size_t)(col0 + wrow) * ldw + k0 + scol;
      __builtin_amdgcn_global_load_lds(
          (const __attribute__((address_space(1))) void*)wsrc,
          (__attribute__((address_space(3))) void*)&Ws[wrow * 64 + scol],
          16, 0, 0);
    }
    __syncthreads();
    #pragma unroll
    for (int kk = 0; kk < 64; kk += 32) {
      bf16x8_t af[2], bfr[4];
      const int kcol = kk + (lane >> 4) * 8;
      const int ar = wave * 32 + (lane & 15);
      const int br = lane & 15;
      #pragma unroll
      for (int m = 0; m < 2; ++m)
        af[m] = *reinterpret_cast<const bf16x8_t*>(&As[(ar + m * 16) * 64 + kcol]);
      #pragma unroll
      for (int n = 0; n < 4; ++n)
        bfr[n] = *reinterpret_cast<const bf16x8_t*>(&Ws[(br + n * 16) * 64 + kcol]);
      #pragma unroll
      for (int m = 0; m < 2; ++m)
        #pragma unroll
        for (int n = 0; n < 4; ++n)
          acc[m][n] = __builtin_amdgcn_mfma_f32_16x16x32_bf16(af[m], bfr[n], acc[m][n], 0, 0, 0);
    }
  }

  // ---- epilogue ----
  float bv[4];
  #pragma unroll
  for (int n = 0; n < 4; ++n)
    bv[n] = bias[col0 + n * 16 + (lane & 15)];

  if (mode == 0) {
    #pragma unroll
    for (int n = 0; n < 4; ++n) {
      const int col = col0 + n * 16 + (lane & 15);
      #pragma unroll
      for (int m = 0; m < 2; ++m) {
        const int rbase = row0 + wave * 32 + m * 16 + (lane >> 4) * 4;
        #pragma unroll
        for (int r = 0; r < 4; ++r)
          C[(size_t)(rbase + r) * ldc + col] = acc[m][n][r] + bv[n];
      }
    }
    return;
  }

  // LSTM epilogue: n-fragment == gate (i,f,g,o); h channel fixed per lane.
  const int hcol = (col0 >> 6) * 16 + (lane & 15);
  #pragma unroll
  for (int m = 0; m < 2; ++m) {
    const int rbase = row0 + wave * 32 + m * 16 + (lane >> 4) * 4;
    #pragma unroll
    for (int r = 0; r < 4; ++r) {
      const size_t idx = (size_t)(rbase + r) * kH + hcol;
      const float gi = acc[m][0][r] + bv[0];
      const float gf = acc[m][1][r] + bv[1];
      const float gg = acc[m][2][r] + bv[2];
      const float go = acc[m][3][r] + bv[3];
      float cp;
      if (mode == 1) cp = first ? 0.f : cbuf[idx];
      else           cp = c_in[idx];
      const float cn = sigm(gf) * cp + sigm(gi) * tanhf(gg);
      const float hn = sigm(go) * tanhf(cn);
      if (mode == 1) {
        cbuf[idx] = cn;
        hb[idx] = f2bf(hn);
        if (last) hmem[idx] = hn;
      } else {
        c_out[idx] = cn;
        h_out[idx] = hn;
      }
    }
  }
}

// ============================================================================
extern "C" void kernel_launch(void* const* d_in, const int* in_sizes, int n_in,
                              void* d_out, int out_size, void* d_ws, size_t ws_size,
                              hipStream_t stream)
{
  const float* x_t      = (const float*)d_in[0];
  const float* h_lstm   = (const float*)d_in[1];
  const float* c_lstm   = (const float*)d_in[2];
  const float* slots    = (const float*)d_in[3];
  const int*   ptr      = (const int*)  d_in[4];
  const float* value_W  = (const float*)d_in[5];
  const float* value_b  = (const float*)d_in[6];
  const float* ed_W     = (const float*)d_in[7];
  const float* ed_b     = (const float*)d_in[8];
  const float* pos_emb  = (const float*)d_in[9];
  const float* lstm_Wih = (const float*)d_in[10];
  const float* lstm_Whh = (const float*)d_in[11];
  const float* lstm_bih = (const float*)d_in[12];
  const float* lstm_bhh = (const float*)d_in[13];
  const float* Wih      = (const float*)d_in[14];
  const float* bih      = (const float*)d_in[15];
  const float* Whh      = (const float*)d_in[16];

  float* out       = (float*)d_out;
  float* h_new     = out;
  float* c_new     = out + (size_t)kB * kH;
  float* h_mem     = out + (size_t)2 * kB * kH;
  float* new_slots = out + (size_t)3 * kB * kH;
  float* new_ptr   = out + (size_t)3 * kB * kH + (size_t)kB * kS * kD;

  // workspace layout (bytes)
  char* ws = (char*)d_ws;
  size_t off = 0;
  auto alloc = [&](size_t bytes) { void* p = ws + off; off += (bytes + 255) & ~(size_t)255; return p; };
  int*   ev        = (int*)  alloc((size_t)kB * 4);
  short* x_b       = (short*)alloc((size_t)kB * kD * 2);
  short* hlstm_b   = (short*)alloc((size_t)kB * kH * 2);
  short* vW_b      = (short*)alloc((size_t)kD * kD * 2);
  short* stepW_b   = (short*)alloc((size_t)kG * (kD + kH) * 2);
  float* stepBias  = (float*)alloc((size_t)kG * 4);
  short* outerW_b  = (short*)alloc((size_t)kG * (kD + kH + kH) * 2);
  float* outerBias = (float*)alloc((size_t)kG * 4);
  float* v_f32     = (float*)alloc((size_t)kB * kD * 4);
  short* h_b       = (short*)alloc((size_t)kB * kH * 2);
  float* c_f32     = (float*)alloc((size_t)kB * kH * 4);
  short* slots_pe  = (short*)alloc((size_t)kB * kS * kD * 2);
  (void)ws_size; (void)in_sizes; (void)n_in; (void)out_size;

  // 1. event flags + new_ptr (f32 exact)
  event_kernel<<<kB / 4, 256, 0, stream>>>(x_t, ed_W, ed_b, ptr, ev, new_ptr);

  // 2. conversions / packing
  f2b_kernel<<<(kB * kD / 4 + 255) / 256, 256, 0, stream>>>(x_t, x_b, kB * kD / 4);
  f2b_kernel<<<(kB * kH / 4 + 255) / 256, 256, 0, stream>>>(h_lstm, hlstm_b, kB * kH / 4);
  f2b_kernel<<<(kD * kD / 4 + 255) / 256, 256, 0, stream>>>(value_W, vW_b, kD * kD / 4);
  packw_gates_kernel<<<(kG * 1024 / 4 + 255) / 256, 256, 0, stream>>>(
      lstm_Wih, kD, lstm_Whh, kH, stepW_b, kG * 1024 / 4);
  packw_gates_kernel<<<(kG * 1536 / 4 + 255) / 256, 256, 0, stream>>>(
      Wih, kD + kH, Whh, kH, outerW_b, kG * 1536 / 4);
  packbias_kernel<<<(kG + 255) / 256, 256, 0, stream>>>(lstm_bih, lstm_bhh, stepBias, kG);
  packbias_kernel<<<(kG + 255) / 256, 256, 0, stream>>>(bih, nullptr, outerBias, kG);

  // 3. v = x @ value_W^T + value_b  (mode 0): grid 32x8 = 256 blocks
  gemm_fused_kernel<<<(kB / 128) * (kD / 64), 256, 0, stream>>>(
      x_b, kD, nullptr, 0, nullptr, 0, 1, vW_b, kD, value_b, 0, kD / 64,
      v_f32, kD, nullptr, nullptr, nullptr, 0, 0, nullptr, nullptr, nullptr);

  // 4. new_slots (f32 out) + slots_pe bf16 staging
  slot_update_kernel<<<(int)((size_t)kB * kS * kD / 4 / 256), 256, 0, stream>>>(
      slots, v_f32, pos_emb, ptr, ev, new_slots, slots_pe);

  // 5. slot-fuser LSTM: 16 sequential steps, ew fused into GEMM epilogue
  //    grid 32x32 = 1024 blocks (4/CU)
  for (int s = 0; s < kS; ++s) {
    const short* a0 = slots_pe + (size_t)s * kD;
    const int first = (s == 0) ? 1 : 0;
    const int last  = (s == kS - 1) ? 1 : 0;
    if (s == 0) {
      gemm_fused_kernel<<<(kB / 128) * (kG / 64), 256, 0, stream>>>(
          a0, kS * kD, nullptr, 0, nullptr, 0, 1, stepW_b, kD + kH, stepBias, 1, kG / 64,
          nullptr, 0, c_f32, h_b, h_mem, first, last, nullptr, nullptr, nullptr);
    } else {
      gemm_fused_kernel<<<(kB / 128) * (kG / 64), 256, 0, stream>>>(
          a0, kS * kD, h_b, kH, nullptr, 0, 2, stepW_b, kD + kH, stepBias, 1, kG / 64,
          nullptr, 0, c_f32, h_b, h_mem, first, last, nullptr, nullptr, nullptr);
    }
  }

  // 6. outer LSTM fused: gates = [x | h_mem | h_lstm] @ [Wih|Whh]^T + bih
  gemm_fused_kernel<<<(kB / 128) * (kG / 64), 256, 0, stream>>>(
      x_b, kD, h_b, kH, hlstm_b, kH, 3, outerW_b, kD + kH + kH, outerBias, 2, kG / 64,
      nullptr, 0, nullptr, nullptr, nullptr, 0, 0, c_lstm, h_new, c_new);
}